// Round 4
// baseline (104384.314 us; speedup 1.0000x reference)
//
#include <hip/hip_runtime.h>

#define BTOT 8192
#define T 512
#define INW 8
#define HID 64
#define G4 256   // 4*HID
#define NB 8     // batch elements per block
#define TS 64    // timesteps per x-chunk staged in LDS

__device__ __forceinline__ float fast_rcp(float x) { return __builtin_amdgcn_rcpf(x); }
__device__ __forceinline__ float sigm_f(float x) { return fast_rcp(1.0f + __expf(-x)); }
__device__ __forceinline__ float tanh_f(float x) { return 1.0f - 2.0f * fast_rcp(__expf(2.0f * x) + 1.0f); }

__global__ __launch_bounds__(256, 3) void lstm_fused_kernel(
    const float* __restrict__ x,      // [B, T, IN]
    const float* __restrict__ W_ih,   // [4H, IN]
    const float* __restrict__ W_hh,   // [4H, H]
    const float* __restrict__ b_ih,   // [4H]
    const float* __restrict__ b_hh,   // [4H]
    const float* __restrict__ W_fc,   // [2, H]
    const float* __restrict__ b_fc,   // [2]
    float* __restrict__ out)          // [B, 2]
{
    __shared__ alignas(16) float xbuf[NB * TS * INW];   // 16 KB
    __shared__ alignas(16) float h_lds[NB * HID];       // 2 KB
    __shared__ alignas(16) float gate_lds[NB * G4];     // 8 KB

    const int tid = threadIdx.x;        // 0..255 == gate row g
    const int g = tid;
    const int batch0 = blockIdx.x * NB;

    // ---- persistent per-thread weights: row g of W_hh held in 16 NAMED
    //      float4 registers (no array => cannot be demoted to scratch) ----
    const float4* whh_row = reinterpret_cast<const float4*>(W_hh) + g * (HID / 4);
#define DECLW(i) float4 w##i = whh_row[i];
    DECLW(0)  DECLW(1)  DECLW(2)  DECLW(3)
    DECLW(4)  DECLW(5)  DECLW(6)  DECLW(7)
    DECLW(8)  DECLW(9)  DECLW(10) DECLW(11)
    DECLW(12) DECLW(13) DECLW(14) DECLW(15)
#undef DECLW

    float4 wihA = reinterpret_cast<const float4*>(W_ih)[g * 2 + 0];
    float4 wihB = reinterpret_cast<const float4*>(W_ih)[g * 2 + 1];
    const float bias = b_ih[g] + b_hh[g];

    // update-phase mapping: this thread owns states (b0,j) and (b1,j)
    const int j  = tid & 63;       // lane id within wave
    const int b0 = tid >> 6;       // 0..3
    const int b1 = b0 + 4;         // 4..7
    float c0 = 0.0f, c1 = 0.0f;

    // wave-uniform activation selector (gate rows 128..191 = g-gate = tanh)
    const bool is_tanh_gate = (g >= 128 && g < 192);

    // init h = 0
    h_lds[tid] = 0.0f;
    h_lds[tid + 256] = 0.0f;   // NB*HID = 512

    const float4* h4 = reinterpret_cast<const float4*>(h_lds);

    #pragma unroll 1
    for (int tc = 0; tc < T / TS; ++tc) {
        __syncthreads();                 // xbuf free; also covers h init at tc=0
        // ---- stage x chunk: NB segments of TS*IN floats, coalesced f4 ----
        {
            const float4* xs = reinterpret_cast<const float4*>(x);
            float4* xd = reinterpret_cast<float4*>(xbuf);
            #pragma unroll
            for (int it = 0; it < (NB * TS * INW / 4) / 256; ++it) {
                int idx = it * 256 + tid;          // float4 index
                int b = idx >> 7;                  // 128 f4 per segment
                int l = idx & 127;
                xd[idx] = xs[(size_t)(batch0 + b) * (T * INW / 4) + tc * (TS * INW / 4) + l];
            }
        }
        __syncthreads();

        #pragma unroll 1
        for (int tt = 0; tt < TS; ++tt) {
            // ---- gate phase: thread g computes gate row g for NB batch elems ----
            float acc[NB];

            // x-projection part (+bias)
            #pragma unroll
            for (int b = 0; b < NB; ++b) {
                const float4* xv = reinterpret_cast<const float4*>(xbuf)
                                   + b * (TS * INW / 4) + tt * 2;
                float4 x0 = xv[0], x1 = xv[1];
                float a = bias;
                a = fmaf(wihA.x, x0.x, a);
                a = fmaf(wihA.y, x0.y, a);
                a = fmaf(wihA.z, x0.z, a);
                a = fmaf(wihA.w, x0.w, a);
                a = fmaf(wihB.x, x1.x, a);
                a = fmaf(wihB.y, x1.y, a);
                a = fmaf(wihB.z, x1.z, a);
                a = fmaf(wihB.w, x1.w, a);
                acc[b] = a;
            }

            // recurrent part: acc[b] += W_hh[g][:] . h[b][:]
            // 16 groups; named weight regs, statically indexed everywhere.
#define KKSTEP(i)                                                        \
            {                                                            \
                _Pragma("unroll")                                        \
                for (int b = 0; b < NB; ++b) {                           \
                    float4 hv = h4[b * (HID / 4) + i];                   \
                    float a = acc[b];                                    \
                    a = fmaf(w##i.x, hv.x, a);                           \
                    a = fmaf(w##i.y, hv.y, a);                           \
                    a = fmaf(w##i.z, hv.z, a);                           \
                    a = fmaf(w##i.w, hv.w, a);                           \
                    acc[b] = a;                                          \
                }                                                        \
            }
            KKSTEP(0)  KKSTEP(1)  KKSTEP(2)  KKSTEP(3)
            KKSTEP(4)  KKSTEP(5)  KKSTEP(6)  KKSTEP(7)
            KKSTEP(8)  KKSTEP(9)  KKSTEP(10) KKSTEP(11)
            KKSTEP(12) KKSTEP(13) KKSTEP(14) KKSTEP(15)
#undef KKSTEP

            // activation (wave-uniform branch) + write gate value
            #pragma unroll
            for (int b = 0; b < NB; ++b) {
                float a = is_tanh_gate ? tanh_f(acc[b]) : sigm_f(acc[b]);
                gate_lds[b * G4 + g] = a;
            }
            __syncthreads();

            // ---- update phase: c,h for (b0,j) and (b1,j) ----
            {
                float iv = gate_lds[b0 * G4 + j];
                float fv = gate_lds[b0 * G4 + 64 + j];
                float gv = gate_lds[b0 * G4 + 128 + j];
                float ov = gate_lds[b0 * G4 + 192 + j];
                c0 = fmaf(fv, c0, iv * gv);
                h_lds[b0 * HID + j] = ov * tanh_f(c0);
            }
            {
                float iv = gate_lds[b1 * G4 + j];
                float fv = gate_lds[b1 * G4 + 64 + j];
                float gv = gate_lds[b1 * G4 + 128 + j];
                float ov = gate_lds[b1 * G4 + 192 + j];
                c1 = fmaf(fv, c1, iv * gv);
                h_lds[b1 * HID + j] = ov * tanh_f(c1);
            }
            __syncthreads();
        }
    }

    // ---- final FC: out[b] = h_last . W_fc[row] + b_fc ----
    {
        float h0 = h_lds[b0 * HID + j];
        float h1 = h_lds[b1 * HID + j];
        float w0 = W_fc[j];
        float w1 = W_fc[HID + j];
        float a0 = h0 * w0, a1 = h0 * w1;
        float a2 = h1 * w0, a3 = h1 * w1;
        #pragma unroll
        for (int off = 32; off > 0; off >>= 1) {
            a0 += __shfl_down(a0, off, 64);
            a1 += __shfl_down(a1, off, 64);
            a2 += __shfl_down(a2, off, 64);
            a3 += __shfl_down(a3, off, 64);
        }
        if (j == 0) {
            float bo0 = b_fc[0], bo1 = b_fc[1];
            out[(size_t)(batch0 + b0) * 2 + 0] = a0 + bo0;
            out[(size_t)(batch0 + b0) * 2 + 1] = a1 + bo1;
            out[(size_t)(batch0 + b1) * 2 + 0] = a2 + bo0;
            out[(size_t)(batch0 + b1) * 2 + 1] = a3 + bo1;
        }
    }
}

extern "C" void kernel_launch(void* const* d_in, const int* in_sizes, int n_in,
                              void* d_out, int out_size, void* d_ws, size_t ws_size,
                              hipStream_t stream) {
    const float* x    = (const float*)d_in[0];
    const float* W_ih = (const float*)d_in[1];
    const float* W_hh = (const float*)d_in[2];
    const float* b_ih = (const float*)d_in[3];
    const float* b_hh = (const float*)d_in[4];
    const float* W_fc = (const float*)d_in[5];
    const float* b_fc = (const float*)d_in[6];
    float* out = (float*)d_out;

    dim3 grid(BTOT / NB);   // 1024 blocks
    dim3 block(256);
    lstm_fused_kernel<<<grid, block, 0, stream>>>(x, W_ih, W_hh, b_ih, b_hh,
                                                  W_fc, b_fc, out);
}

// Round 5
// 2791.584 us; speedup vs baseline: 37.3925x; 37.3925x over previous
//
#include <hip/hip_runtime.h>

#define BTOT 8192
#define T 512
#define INW 8
#define HID 64
#define G4 256   // 4*HID
#define NB 8     // batch elements per block
#define TS 64    // timesteps per x-chunk staged in LDS

__device__ __forceinline__ float fast_rcp(float x) { return __builtin_amdgcn_rcpf(x); }
__device__ __forceinline__ float sigm_f(float x) { return fast_rcp(1.0f + __expf(-x)); }
__device__ __forceinline__ float tanh_f(float x) { return 1.0f - 2.0f * fast_rcp(__expf(2.0f * x) + 1.0f); }

// Split-K LSTM: 512 threads; thread (row = tid>>1, half = tid&1) holds HALF a
// gate row of W_hh (32 floats). Live set ~58 VGPRs -> fits any occupancy
// target the backend picks; waves_per_eu(2,4) pins budget at 128 so the
// scheduler has hoist slack without spilling (rounds 1-4 post-mortems).
__attribute__((amdgpu_waves_per_eu(2, 4)))
__global__ __launch_bounds__(512) void lstm_fused_kernel(
    const float* __restrict__ x,      // [B, T, IN]
    const float* __restrict__ W_ih,   // [4H, IN]
    const float* __restrict__ W_hh,   // [4H, H]
    const float* __restrict__ b_ih,   // [4H]
    const float* __restrict__ b_hh,   // [4H]
    const float* __restrict__ W_fc,   // [2, H]
    const float* __restrict__ b_fc,   // [2]
    float* __restrict__ out)          // [B, 2]
{
    __shared__ alignas(16) float xbuf[NB * TS * INW];   // 16 KB
    __shared__ alignas(16) float h_lds[NB * HID];       // 2 KB
    __shared__ alignas(16) float gate_lds[NB * G4];     // 8 KB

    const int tid  = threadIdx.x;       // 0..511
    const int row  = tid >> 1;          // gate row 0..255
    const int half = tid & 1;           // which K-half of the row
    const int batch0 = blockIdx.x * NB;

    // ---- per-thread persistent weights: 8 named float4 = 32 floats ----
    const float4* whh_half = reinterpret_cast<const float4*>(W_hh) + row * (HID / 4) + half * 8;
#define DECLW(i) float4 w##i = whh_half[i];
    DECLW(0) DECLW(1) DECLW(2) DECLW(3) DECLW(4) DECLW(5) DECLW(6) DECLW(7)
#undef DECLW
    float4 wih = reinterpret_cast<const float4*>(W_ih)[row * 2 + half];
    const float bias = half ? b_hh[row] : b_ih[row];   // halves sum to b_ih+b_hh

    // update-phase mapping: thread owns state (bb, j); wave == batch elem
    const int j  = tid & 63;
    const int bb = tid >> 6;            // 0..7
    float c = 0.0f;

    // wave-uniform activation selector (rows 128..191 => tid 256..383 => waves 4,5)
    const bool is_tanh_gate = (row >= 128 && row < 192);

    h_lds[tid & 511] = 0.0f;            // NB*HID == 512 exactly

    const float4* h4 = reinterpret_cast<const float4*>(h_lds);

    #pragma unroll 1
    for (int tc = 0; tc < T / TS; ++tc) {
        __syncthreads();                // xbuf free; covers h init at tc=0
        // ---- stage x chunk: 1024 float4, 512 threads, 2 iters, coalesced ----
        {
            const float4* xs = reinterpret_cast<const float4*>(x);
            float4* xd = reinterpret_cast<float4*>(xbuf);
            #pragma unroll
            for (int it = 0; it < 2; ++it) {
                int idx = it * 512 + tid;          // float4 index
                int b = idx >> 7;                  // 128 f4 per batch segment
                int l = idx & 127;
                xd[idx] = xs[(size_t)(batch0 + b) * (T * INW / 4) + tc * (TS * INW / 4) + l];
            }
        }
        __syncthreads();

        #pragma unroll 1
        for (int tt = 0; tt < TS; ++tt) {
            float acc[NB];

            // x-projection (this half's 4 input dims) + half-bias
            #pragma unroll
            for (int b = 0; b < NB; ++b) {
                float4 xv = *(reinterpret_cast<const float4*>(xbuf)
                              + b * (TS * INW / 4) + tt * 2 + half);
                float a = bias;
                a = fmaf(wih.x, xv.x, a);
                a = fmaf(wih.y, xv.y, a);
                a = fmaf(wih.z, xv.z, a);
                a = fmaf(wih.w, xv.w, a);
                acc[b] = a;
            }

            // recurrent partial dot: 8 float4 groups over this half of h
#define KKSTEP(i)                                                        \
            {                                                            \
                _Pragma("unroll")                                        \
                for (int b = 0; b < NB; ++b) {                           \
                    float4 hv = h4[b * (HID / 4) + half * 8 + i];        \
                    float a = acc[b];                                    \
                    a = fmaf(w##i.x, hv.x, a);                           \
                    a = fmaf(w##i.y, hv.y, a);                           \
                    a = fmaf(w##i.z, hv.z, a);                           \
                    a = fmaf(w##i.w, hv.w, a);                           \
                    acc[b] = a;                                          \
                }                                                        \
            }
            KKSTEP(0) KKSTEP(1) KKSTEP(2) KKSTEP(3)
            KKSTEP(4) KKSTEP(5) KKSTEP(6) KKSTEP(7)
#undef KKSTEP

            // combine the two halves (lane^1): both threads get full sums
            #pragma unroll
            for (int b = 0; b < NB; ++b)
                acc[b] += __shfl_xor(acc[b], 1, 64);

            // activation split: half0 -> b 0..3, half1 -> b 4..7.
            // acc[] indices STATIC (rule #20); half-select via cndmask.
            {
                float v0 = half ? acc[4] : acc[0];
                float v1 = half ? acc[5] : acc[1];
                float v2 = half ? acc[6] : acc[2];
                float v3 = half ? acc[7] : acc[3];
                float a0, a1, a2, a3;
                if (is_tanh_gate) {
                    a0 = tanh_f(v0); a1 = tanh_f(v1); a2 = tanh_f(v2); a3 = tanh_f(v3);
                } else {
                    a0 = sigm_f(v0); a1 = sigm_f(v1); a2 = sigm_f(v2); a3 = sigm_f(v3);
                }
                float* gp = gate_lds + half * 4 * G4 + row;
                gp[0 * G4] = a0;
                gp[1 * G4] = a1;
                gp[2 * G4] = a2;
                gp[3 * G4] = a3;
            }
            __syncthreads();

            // ---- update phase: one state (bb, j) per thread ----
            {
                float iv = gate_lds[bb * G4 + j];
                float fv = gate_lds[bb * G4 + 64 + j];
                float gv = gate_lds[bb * G4 + 128 + j];
                float ov = gate_lds[bb * G4 + 192 + j];
                c = fmaf(fv, c, iv * gv);
                h_lds[bb * HID + j] = ov * tanh_f(c);
            }
            __syncthreads();
        }
    }

    // ---- final FC: wave bb reduces batch elem bb over 64 lanes ----
    {
        float h  = h_lds[bb * HID + j];
        float p0 = h * W_fc[j];
        float p1 = h * W_fc[HID + j];
        #pragma unroll
        for (int off = 32; off > 0; off >>= 1) {
            p0 += __shfl_down(p0, off, 64);
            p1 += __shfl_down(p1, off, 64);
        }
        if (j == 0) {
            out[(size_t)(batch0 + bb) * 2 + 0] = p0 + b_fc[0];
            out[(size_t)(batch0 + bb) * 2 + 1] = p1 + b_fc[1];
        }
    }
}

extern "C" void kernel_launch(void* const* d_in, const int* in_sizes, int n_in,
                              void* d_out, int out_size, void* d_ws, size_t ws_size,
                              hipStream_t stream) {
    const float* x    = (const float*)d_in[0];
    const float* W_ih = (const float*)d_in[1];
    const float* W_hh = (const float*)d_in[2];
    const float* b_ih = (const float*)d_in[3];
    const float* b_hh = (const float*)d_in[4];
    const float* W_fc = (const float*)d_in[5];
    const float* b_fc = (const float*)d_in[6];
    float* out = (float*)d_out;

    dim3 grid(BTOT / NB);   // 1024 blocks
    dim3 block(512);
    lstm_fused_kernel<<<grid, block, 0, stream>>>(x, W_ih, W_hh, b_ih, b_hh,
                                                  W_fc, b_fc, out);
}